// Round 9
// baseline (446.769 us; speedup 1.0000x reference)
//
#include <hip/hip_runtime.h>
#include <hip/hip_bf16.h>
#include <hip/hip_cooperative_groups.h>

namespace cg = cooperative_groups;

#define NN 25000
#define NE 100000
#define NG 512
#define NPAD 25024
#define NEP 100032          // padded msg rows
#define NT 6250             // edge tiles per branch (NE/16, exact)
#define XL (2 * NPAD * 32)  // elements per x layer slot (both branches)
#define BLK 256

typedef __attribute__((ext_vector_type(8))) short short8;
typedef __attribute__((ext_vector_type(4))) float f32x4;

__device__ __forceinline__ float bf2f(unsigned short u) {
    union { unsigned u; float f; } v; v.u = (unsigned)u << 16; return v.f;
}
__device__ __forceinline__ unsigned short f2bf(float f) {       // native RNE cast
    union { __hip_bfloat16 b; unsigned short u; } c;
    c.b = __float2bfloat16(f);
    return c.u;
}
__device__ __forceinline__ unsigned pk2(float lo, float hi) {   // packed bf16 pair
    __hip_bfloat162 h2;
    h2.x = __float2bfloat16(lo);
    h2.y = __float2bfloat16(hi);
    union { __hip_bfloat162 h; unsigned u; } c; c.h = h2; return c.u;
}

#define S1 (4 * 17 * 1024)      // Wt build items
#define S2V (2 * NN * 8)        // float4-vectorized x cast items
#define S3 (2 * NN)             // hist zero
#define S4 (NG * 64 / 4)        // gbuf zero (float4)

struct MKArgs {
    const float* x0[2]; const float* ea[2];
    const int* eidx[2]; const int* batch[2];
    const float* w1[4]; const float* b1[4];     // index br*2+L
    const float* w2[4]; const float* b2[4];
    const float* root[4]; const float* bias[4];
    const float* lw0; const float* lb0; const float* lw1; const float* lb1;
    float* out;
    unsigned short* Wt; unsigned short* xb; unsigned short* msg;
    int* hist; int* ptr; int* slot; float* gbuf;
};

// ---------------- phase bodies (shared by mega + fallback) --------------------

__device__ __forceinline__ void prep_body(const MKArgs& a, int idx) {
    if (idx < S1) {
        int L = idx / (17 * 1024);
        int r = idx % (17 * 1024);
        int s = r >> 10, o = (r >> 5) & 31, i = r & 31;
        float v = (s < 16) ? a.w2[L][s * 1024 + i * 32 + o] : a.b2[L][i * 32 + o];
        a.Wt[idx] = f2bf(v);
        return;
    }
    idx -= S1;
    if (idx < S2V) {
        int br = idx / (NN * 8);
        int q = idx % (NN * 8);
        float4 v = *(const float4*)(a.x0[br] + (size_t)q * 4);
        unsigned* dst = (unsigned*)(a.xb + (size_t)br * NPAD * 32 + (size_t)q * 4);
        dst[0] = pk2(v.x, v.y);
        dst[1] = pk2(v.z, v.w);
        return;
    }
    idx -= S2V;
    if (idx < S3) { a.hist[idx] = 0; return; }
    idx -= S3;
    if (idx < S4)
        *(float4*)(a.gbuf + (size_t)idx * 4) = make_float4(0.f, 0.f, 0.f, 0.f);
}

__device__ __forceinline__ void hist_body(const MKArgs& a, int idx) {
    int br = idx >= NE, e = idx - br * NE;
    a.slot[idx] = atomicAdd(&a.hist[br * NN + a.eidx[br][NE + e]], 1);
}

// 256-thread scan over one branch's hist (caller: one block per branch)
__device__ __forceinline__ void scan_body(const MKArgs& a, int br, int tid, int* wsum) {
    const int* h = a.hist + br * NN;
    int* p = a.ptr + br * (NN + 1);
    int base = tid * 98;
    int s = 0;
    for (int j = 0; j < 98; ++j) { int ii = base + j; if (ii < NN) s += h[ii]; }
    int w = tid >> 6, ln = tid & 63;
    int v = s;
    #pragma unroll
    for (int d = 1; d < 64; d <<= 1) { int u = __shfl_up(v, d, 64); if (ln >= d) v += u; }
    if (ln == 63) wsum[w] = v;
    __syncthreads();
    int run = v - s;
    for (int k = 0; k < w; ++k) run += wsum[k];
    for (int j = 0; j < 98; ++j) {
        int ii = base + j;
        if (ii < NN) { p[ii] = run; run += h[ii]; }
    }
    if (tid == 255) p[NN] = run;
}

// one 16-edge tile; W* = register-resident weight tiles
__device__ __forceinline__ void edge_tile(const MKArgs& a, int br, int L, int t,
        int lr, int kg, int lane, const short8* WA, const short8* WB,
        const float* w1r, const float* b1r, unsigned* trw) {
    const int* eidx = a.eidx[br];
    const unsigned short* xc = a.xb + (size_t)L * XL + (size_t)br * NPAD * 32;
    int e = t * 16 + lr;
    int src = eidx[e];
    int rk = 0;
    if (kg == 0) rk = a.ptr[br * (NN + 1) + eidx[NE + e]] + a.slot[br * NE + e];

    short8 xs8 = *(const short8*)(xc + (size_t)src * 32 + kg * 8);
    float xf[8];
    #pragma unroll
    for (int j = 0; j < 8; ++j) xf[j] = bf2f((unsigned short)xs8[j]);

    const float* ea = a.ea[br];
    float4 ea0 = *(const float4*)(ea + (size_t)e * 8);
    float4 ea1 = *(const float4*)(ea + (size_t)e * 8 + 4);
    float hreg[4];
    #pragma unroll
    for (int r = 0; r < 4; ++r) {
        float h = b1r[r];
        h += ea0.x * w1r[r * 8 + 0]; h += ea0.y * w1r[r * 8 + 1];
        h += ea0.z * w1r[r * 8 + 2]; h += ea0.w * w1r[r * 8 + 3];
        h += ea1.x * w1r[r * 8 + 4]; h += ea1.y * w1r[r * 8 + 5];
        h += ea1.z * w1r[r * 8 + 6]; h += ea1.w * w1r[r * 8 + 7];
        hreg[r] = fmaxf(h, 0.f);
    }

    f32x4 acc0 = {0.f, 0.f, 0.f, 0.f}, acc1 = {0.f, 0.f, 0.f, 0.f};
    #pragma unroll
    for (int s = 0; s < 17; ++s) {
        short8 y;
        if (s < 16) {
            float hs = __shfl(hreg[s & 3], lr + ((s >> 2) << 4), 64);
            union { unsigned u[4]; short8 v; } yy;
            yy.u[0] = pk2(hs * xf[0], hs * xf[1]);
            yy.u[1] = pk2(hs * xf[2], hs * xf[3]);
            yy.u[2] = pk2(hs * xf[4], hs * xf[5]);
            yy.u[3] = pk2(hs * xf[6], hs * xf[7]);
            y = yy.v;
        } else {
            y = xs8;                        // b2 slice: h == 1
        }
        acc0 = __builtin_amdgcn_mfma_f32_16x16x32_bf16(WA[s], y, acc0, 0, 0, 0);
        acc1 = __builtin_amdgcn_mfma_f32_16x16x32_bf16(WB[s], y, acc1, 0, 0, 0);
    }
    // transpose via wave-private LDS, one dwordx4 store per lane
    trw[lr * 16 + kg * 2    ] = pk2(acc0[0], acc0[1]);
    trw[lr * 16 + kg * 2 + 1] = pk2(acc0[2], acc0[3]);
    trw[lr * 16 + 8 + kg * 2    ] = pk2(acc1[0], acc1[1]);
    trw[lr * 16 + 8 + kg * 2 + 1] = pk2(acc1[2], acc1[3]);
    int rkb = __shfl(rk, lane >> 2, 64);
    uint4 val = *(uint4*)&trw[(lane >> 2) * 16 + (lane & 3) * 4];
    unsigned short* mg = a.msg + (size_t)br * NEP * 32;
    *(uint4*)(mg + (size_t)rkb * 32 + (lane & 3) * 8) = val;
}

__device__ __forceinline__ void gather_body(const MKArgs& a, int L, int gw, int o) {
    int br = gw >= NN, n = gw - br * NN;
    int k4 = br * 2 + L;
    const int* p = a.ptr + br * (NN + 1);
    int lo = p[n], hi = p[n + 1];
    const unsigned short* m = a.msg + (size_t)br * NEP * 32;
    float sum = 0.f;
    for (int j = lo; j < hi; ++j) sum += bf2f(m[(size_t)j * 32 + o]);
    float xv = bf2f(a.xb[(size_t)L * XL + ((size_t)br * NPAD + n) * 32 + o]);
    const float* R = a.root[k4];
    float rsum = 0.f;
    #pragma unroll
    for (int i = 0; i < 32; ++i) rsum += __shfl(xv, i, 32) * R[i * 32 + o];
    float v = fmaxf(sum + rsum + a.bias[k4][o], 0.f);
    if (L == 0) {
        a.xb[(size_t)XL + ((size_t)br * NPAD + n) * 32 + o] = f2bf(v);
    } else {
        atomicMax((int*)&a.gbuf[(size_t)a.batch[br][n] * 64 + br * 32 + o],
                  __float_as_int(v));
    }
}

__device__ __forceinline__ void final_body(const MKArgs& a, int g, int j) {
    const float* xr = a.gbuf + (size_t)g * 64;
    float y = a.lb0[j];
    for (int i = 0; i < 64; ++i) y += xr[i] * a.lw0[i * 64 + j];
    float t = y * a.lw1[j];
    #pragma unroll
    for (int off = 32; off > 0; off >>= 1) t += __shfl_down(t, off, 64);
    if (j == 0) a.out[g] = t + a.lb1[0];
}

// ---------------- cooperative mega-kernel (grid-size agnostic, grid even) -----
__global__ __launch_bounds__(BLK, 2) void mega_kernel(MKArgs a) {
    cg::grid_group grid = cg::this_grid();
    __shared__ unsigned tr[4][256];
    __shared__ int wsum[4];
    const int tid = threadIdx.x;
    const int bid = blockIdx.x;
    const int nb  = gridDim.x;
    const int gs  = nb * BLK;
    const int gtid = bid * BLK + tid;

    for (int idx = gtid; idx < S1 + S2V + S3 + S4; idx += gs) prep_body(a, idx);
    grid.sync();

    for (int idx = gtid; idx < 2 * NE; idx += gs) hist_body(a, idx);
    grid.sync();

    if (bid < 2) scan_body(a, bid, tid, wsum);
    grid.sync();

    int wv = tid >> 6, lane = tid & 63;
    int lr = lane & 15, kg = lane >> 4;
    int br = bid & 1, bb2 = bid >> 1;
    int strideT = (nb >> 1) * 4;

    for (int L = 0; L < 2; ++L) {
        {   // edge phase: W tiles resident in registers
            int k4 = br * 2 + L;
            const unsigned short* W = a.Wt + (size_t)k4 * 17 * 1024;
            short8 WA[17], WB[17];
            #pragma unroll
            for (int s = 0; s < 17; ++s) {
                WA[s] = *(const short8*)(W + (size_t)s * 1024 + lr * 32 + kg * 8);
                WB[s] = *(const short8*)(W + (size_t)s * 1024 + (16 + lr) * 32 + kg * 8);
            }
            float w1r[32], b1r[4];
            #pragma unroll
            for (int r = 0; r < 4; ++r) {
                b1r[r] = a.b1[k4][kg * 4 + r];
                #pragma unroll
                for (int i = 0; i < 8; ++i) w1r[r * 8 + i] = a.w1[k4][i * 16 + kg * 4 + r];
            }
            for (int t = bb2 * 4 + wv; t < NT; t += strideT)
                edge_tile(a, br, L, t, lr, kg, lane, WA, WB, w1r, b1r, tr[wv]);
        }
        grid.sync();

        for (int gw = gtid >> 5; gw < 2 * NN; gw += gs / 32)
            gather_body(a, L, gw, tid & 31);
        grid.sync();
    }

    if (tid < 64)
        for (int g = bid; g < NG; g += nb) final_body(a, g, tid);
}

// ---------------- fallback kernels (round-7 verified structure) ---------------
__global__ __launch_bounds__(256) void fb_prep(MKArgs a) {
    int idx = blockIdx.x * 256 + threadIdx.x;
    if (idx < S1 + S2V + S3 + S4) prep_body(a, idx);
}
__global__ __launch_bounds__(256) void fb_hist(MKArgs a) {
    int idx = blockIdx.x * 256 + threadIdx.x;
    if (idx < 2 * NE) hist_body(a, idx);
}
__global__ __launch_bounds__(256) void fb_scan(MKArgs a) {
    __shared__ int wsum[4];
    scan_body(a, blockIdx.x, threadIdx.x, wsum);
}
__global__ __launch_bounds__(256, 2) void fb_edge(MKArgs a, int L) {
    __shared__ unsigned tr[4][256];
    int tid = threadIdx.x;
    int wv = tid >> 6, lane = tid & 63;
    int lr = lane & 15, kg = lane >> 4;
    int br = blockIdx.x >> 8, bb = blockIdx.x & 255;
    int k4 = br * 2 + L;
    const unsigned short* W = a.Wt + (size_t)k4 * 17 * 1024;
    short8 WA[17], WB[17];
    #pragma unroll
    for (int s = 0; s < 17; ++s) {
        WA[s] = *(const short8*)(W + (size_t)s * 1024 + lr * 32 + kg * 8);
        WB[s] = *(const short8*)(W + (size_t)s * 1024 + (16 + lr) * 32 + kg * 8);
    }
    float w1r[32], b1r[4];
    #pragma unroll
    for (int r = 0; r < 4; ++r) {
        b1r[r] = a.b1[k4][kg * 4 + r];
        #pragma unroll
        for (int i = 0; i < 8; ++i) w1r[r * 8 + i] = a.w1[k4][i * 16 + kg * 4 + r];
    }
    for (int t = bb * 4 + wv; t < NT; t += 1024)
        edge_tile(a, br, L, t, lr, kg, lane, WA, WB, w1r, b1r, tr[wv]);
}
__global__ __launch_bounds__(256) void fb_gather(MKArgs a, int L) {
    int gw = (blockIdx.x * 256 + threadIdx.x) >> 5;
    if (gw < 2 * NN) gather_body(a, L, gw, threadIdx.x & 31);
}
__global__ __launch_bounds__(64) void fb_final(MKArgs a) {
    final_body(a, blockIdx.x, threadIdx.x);
}

static size_t aln(size_t v) { return (v + 255) & ~(size_t)255; }

extern "C" void kernel_launch(void* const* d_in, const int* in_sizes, int n_in,
                              void* d_out, int out_size, void* d_ws, size_t ws_size,
                              hipStream_t stream) {
    (void)in_sizes; (void)n_in; (void)out_size; (void)ws_size;
    char* w = (char*)d_ws;
    unsigned short* Wt  = (unsigned short*)w; w += aln((size_t)S1 * 2);
    unsigned short* xb  = (unsigned short*)w; w += aln((size_t)2 * XL * 2);
    unsigned short* msg = (unsigned short*)w; w += aln((size_t)2 * NEP * 32 * 2);
    int* hist = (int*)w; w += aln((size_t)2 * NN * 4);
    int* ptr  = (int*)w; w += aln((size_t)2 * (NN + 1) * 4);
    int* slot = (int*)w; w += aln((size_t)2 * NE * 4);
    float* gbuf = (float*)w; w += aln((size_t)NG * 64 * 4);

    MKArgs a;
    for (int br = 0; br < 2; ++br) {
        a.x0[br]    = (const float*)d_in[br];
        a.ea[br]    = (const float*)d_in[2 + br];
        a.eidx[br]  = (const int*)d_in[4 + br];
        a.batch[br] = (const int*)d_in[6 + br];
        for (int L = 0; L < 2; ++L) {
            int base = 8 + br * 12 + L * 6;
            int k = br * 2 + L;
            a.w1[k]   = (const float*)d_in[base + 0];
            a.b1[k]   = (const float*)d_in[base + 1];
            a.w2[k]   = (const float*)d_in[base + 2];
            a.b2[k]   = (const float*)d_in[base + 3];
            a.root[k] = (const float*)d_in[base + 4];
            a.bias[k] = (const float*)d_in[base + 5];
        }
    }
    a.lw0 = (const float*)d_in[32];
    a.lb0 = (const float*)d_in[33];
    a.lw1 = (const float*)d_in[34];
    a.lb1 = (const float*)d_in[35];
    a.out = (float*)d_out;
    a.Wt = Wt; a.xb = xb; a.msg = msg;
    a.hist = hist; a.ptr = ptr; a.slot = slot; a.gbuf = gbuf;

    // size cooperative grid from the runtime's own occupancy oracle
    bool coop_done = false;
    int maxBlk = 0;
    hipError_t qerr = hipOccupancyMaxActiveBlocksPerMultiprocessor(&maxBlk, mega_kernel, BLK, 0);
    if (qerr == hipSuccess && maxBlk >= 1) {
        hipDeviceProp_t props;
        int dev = 0;
        if (hipGetDevice(&dev) == hipSuccess &&
            hipGetDeviceProperties(&props, dev) == hipSuccess) {
            long g = (long)maxBlk * props.multiProcessorCount;
            if (g > 512) g = 512;
            g &= ~1L;                          // even (parity branch split)
            if (g >= 2) {
                void* params[] = { (void*)&a };
                hipError_t e = hipLaunchCooperativeKernel(mega_kernel,
                        dim3((unsigned)g), dim3(BLK), params, 0u, stream);
                coop_done = (e == hipSuccess);
            }
        }
    }

    if (!coop_done) {   // verified round-7 path
        fb_prep<<<(S1 + S2V + S3 + S4 + 255) / 256, 256, 0, stream>>>(a);
        fb_hist<<<(2 * NE + 255) / 256, 256, 0, stream>>>(a);
        fb_scan<<<2, 256, 0, stream>>>(a);
        for (int L = 0; L < 2; ++L) {
            fb_edge<<<512, 256, 0, stream>>>(a, L);
            fb_gather<<<6250, 256, 0, stream>>>(a, L);
        }
        fb_final<<<NG, 64, 0, stream>>>(a);
    }
}

// Round 10
// 110.955 us; speedup vs baseline: 4.0266x; 4.0266x over previous
//
#include <hip/hip_runtime.h>
#include <hip/hip_bf16.h>

#define NN 25000
#define NE 100000
#define NG 512
#define NPAD 25024
#define NEP 100032          // padded msg rows
#define NT 6250             // edge tiles per branch (NE/16, exact)
#define XL (2 * NPAD * 32)  // elements per x layer slot (both branches)

typedef __attribute__((ext_vector_type(8))) short short8;
typedef __attribute__((ext_vector_type(4))) float f32x4;

__device__ __forceinline__ float bf2f(unsigned short u) {
    union { unsigned u; float f; } v; v.u = (unsigned)u << 16; return v.f;
}
__device__ __forceinline__ unsigned short f2bf(float f) {       // native RNE cast
    union { __hip_bfloat16 b; unsigned short u; } c;
    c.b = __float2bfloat16(f);
    return c.u;
}
__device__ __forceinline__ unsigned pk2(float lo, float hi) {   // packed bf16 pair
    __hip_bfloat162 h2;
    h2.x = __float2bfloat16(lo);
    h2.y = __float2bfloat16(hi);
    union { __hip_bfloat162 h; unsigned u; } c; c.h = h2; return c.u;
}

// ---- prep: Wt bf16 (17 slices: 16 w2 + b2), x0 cast (x4 vec), hist+gbuf zero --
struct PrepArgs {
    const float* w2[4]; const float* b2[4];
    const float* x0[2];
};
#define S1 (4 * 17 * 1024)
#define S2V (2 * NN * 8)        // float4-vectorized x cast items
#define S3 (2 * NN)
#define S4 (NG * 64 / 4)        // gbuf zero, float4 items
__global__ __launch_bounds__(256) void prep_kernel(PrepArgs pa,
        unsigned short* __restrict__ Wt, unsigned short* __restrict__ xb,
        int* __restrict__ hist, float* __restrict__ gbuf) {
    int idx = blockIdx.x * 256 + threadIdx.x;
    if (idx < S1) {
        int L = idx / (17 * 1024);
        int r = idx % (17 * 1024);
        int s = r >> 10, o = (r >> 5) & 31, i = r & 31;
        float v = (s < 16) ? pa.w2[L][s * 1024 + i * 32 + o] : pa.b2[L][i * 32 + o];
        Wt[idx] = f2bf(v);
        return;
    }
    idx -= S1;
    if (idx < S2V) {
        int br = idx / (NN * 8);
        int q = idx % (NN * 8);
        float4 v = *(const float4*)(pa.x0[br] + (size_t)q * 4);
        unsigned* dst = (unsigned*)(xb + (size_t)br * NPAD * 32 + (size_t)q * 4);
        dst[0] = pk2(v.x, v.y);
        dst[1] = pk2(v.z, v.w);
        return;
    }
    idx -= S2V;
    if (idx < S3) { hist[idx] = 0; return; }
    idx -= S3;
    if (idx < S4) {
        float4 z = make_float4(0.f, 0.f, 0.f, 0.f);
        *(float4*)(gbuf + (size_t)idx * 4) = z;
    }
}

// ---------------- CSR: hist + within-dst slot ---------------------------------
__global__ __launch_bounds__(256) void hist_kernel(const int* __restrict__ ep,
        const int* __restrict__ ed, int* __restrict__ hist, int* __restrict__ slot) {
    int idx = blockIdx.x * 256 + threadIdx.x;
    if (idx >= 2 * NE) return;
    int br = idx >= NE, e = idx - br * NE;
    const int* ei = br ? ed : ep;
    slot[idx] = atomicAdd(&hist[br * NN + ei[NE + e]], 1);
}

// shfl-based scan: 1024 threads x 25 elems, 2 blocks (one per branch) [r6-verified]
__global__ __launch_bounds__(1024) void scan_kernel(const int* __restrict__ hist,
        int* __restrict__ ptr) {
    int br = blockIdx.x, t = threadIdx.x;
    const int* h = hist + br * NN;
    int* p = ptr + br * (NN + 1);
    int base = t * 25;
    int loc[25]; int s = 0;
    if (base < NN) {
        #pragma unroll
        for (int j = 0; j < 25; ++j) { loc[j] = h[base + j]; s += loc[j]; }
    }
    int w = t >> 6, ln = t & 63;
    int v = s;
    #pragma unroll
    for (int d = 1; d < 64; d <<= 1) {
        int u = __shfl_up(v, d, 64);
        if (ln >= d) v += u;
    }
    __shared__ int wsum[16];
    if (ln == 63) wsum[w] = v;
    __syncthreads();
    if (t < 16) {
        int x = wsum[t];
        #pragma unroll
        for (int d = 1; d < 16; d <<= 1) {
            int u = __shfl_up(x, d, 16);
            if ((t & 15) >= d) x += u;
        }
        wsum[t] = x;
    }
    __syncthreads();
    int run = (w ? wsum[w - 1] : 0) + (v - s);
    if (base < NN) {
        #pragma unroll
        for (int j = 0; j < 25; ++j) { p[base + j] = run; run += loc[j]; }
    }
    if (t == 0) p[NN] = wsum[15];
}

// ---------------- edge: msg[rank(e)] = [w2|b2]^T (h(ea) (x) x[src]) -----------
// W resident in VGPRs (34 x short8); grid-stride over 16-edge tiles.
// Output rows written at CSR rank -> gather streams sequentially. [r7-verified]
struct EdgeArgs {
    const float* ea[2]; const int* eidx[2];
    const float* w1[2]; const float* b1[2];
};
__global__ __launch_bounds__(256, 2) void edge_kernel(EdgeArgs A, int L,
        const unsigned short* __restrict__ Wt,
        const unsigned short* __restrict__ xb,
        const int* __restrict__ ptr, const int* __restrict__ slot,
        unsigned short* __restrict__ msg) {
    __shared__ unsigned tr[4][256];
    int br = blockIdx.x >> 8;          // 512 blocks: low 256 = branch 0
    int bb = blockIdx.x & 255;
    const float* ea   = A.ea[br];
    const int*   eidx = A.eidx[br];
    const float* w1   = A.w1[br];
    const float* b1   = A.b1[br];
    const unsigned short* W  = Wt + (size_t)(br * 2 + L) * 17 * 1024;
    const unsigned short* xc = xb + (size_t)L * XL + (size_t)br * NPAD * 32;
    const int* pt = ptr + br * (NN + 1);
    const int* sl = slot + br * NE;
    unsigned short* mg = msg + (size_t)br * NEP * 32;

    int tid = threadIdx.x;
    int wv = tid >> 6, lane = tid & 63;
    int lr = lane & 15, kg = lane >> 4;

    // W tiles resident in registers for the whole kernel
    short8 WA[17], WB[17];
    #pragma unroll
    for (int s = 0; s < 17; ++s) {
        WA[s] = *(const short8*)(W + (size_t)s * 1024 + lr * 32 + kg * 8);
        WB[s] = *(const short8*)(W + (size_t)s * 1024 + (16 + lr) * 32 + kg * 8);
    }
    // w1 columns for this lane's 4 k-values
    float w1r[32], b1r[4];
    #pragma unroll
    for (int r = 0; r < 4; ++r) {
        b1r[r] = b1[kg * 4 + r];
        #pragma unroll
        for (int i = 0; i < 8; ++i) w1r[r * 8 + i] = w1[i * 16 + kg * 4 + r];
    }

    for (int t = bb * 4 + wv; t < NT; t += 1024) {
        int e = t * 16 + lr;
        int src = eidx[e];
        int rk = 0;
        if (kg == 0) rk = pt[eidx[NE + e]] + sl[e];

        short8 xs8 = *(const short8*)(xc + (size_t)src * 32 + kg * 8);
        float xf[8];
        #pragma unroll
        for (int j = 0; j < 8; ++j) xf[j] = bf2f((unsigned short)xs8[j]);

        float4 ea0 = *(const float4*)(ea + (size_t)e * 8);
        float4 ea1 = *(const float4*)(ea + (size_t)e * 8 + 4);
        float hreg[4];
        #pragma unroll
        for (int r = 0; r < 4; ++r) {
            float h = b1r[r];
            h += ea0.x * w1r[r * 8 + 0]; h += ea0.y * w1r[r * 8 + 1];
            h += ea0.z * w1r[r * 8 + 2]; h += ea0.w * w1r[r * 8 + 3];
            h += ea1.x * w1r[r * 8 + 4]; h += ea1.y * w1r[r * 8 + 5];
            h += ea1.z * w1r[r * 8 + 6]; h += ea1.w * w1r[r * 8 + 7];
            hreg[r] = fmaxf(h, 0.f);
        }

        f32x4 acc0 = {0.f, 0.f, 0.f, 0.f}, acc1 = {0.f, 0.f, 0.f, 0.f};
        #pragma unroll
        for (int s = 0; s < 17; ++s) {
            short8 y;
            if (s < 16) {
                float hs = __shfl(hreg[s & 3], lr + ((s >> 2) << 4), 64);
                union { unsigned u[4]; short8 v; } yy;
                yy.u[0] = pk2(hs * xf[0], hs * xf[1]);
                yy.u[1] = pk2(hs * xf[2], hs * xf[3]);
                yy.u[2] = pk2(hs * xf[4], hs * xf[5]);
                yy.u[3] = pk2(hs * xf[6], hs * xf[7]);
                y = yy.v;
            } else {
                y = xs8;                    // b2 slice: h == 1
            }
            acc0 = __builtin_amdgcn_mfma_f32_16x16x32_bf16(WA[s], y, acc0, 0, 0, 0);
            acc1 = __builtin_amdgcn_mfma_f32_16x16x32_bf16(WB[s], y, acc1, 0, 0, 0);
        }
        // transpose through wave-private LDS, then one dwordx4 store per lane
        tr[wv][lr * 16 + kg * 2    ] = pk2(acc0[0], acc0[1]);
        tr[wv][lr * 16 + kg * 2 + 1] = pk2(acc0[2], acc0[3]);
        tr[wv][lr * 16 + 8 + kg * 2    ] = pk2(acc1[0], acc1[1]);
        tr[wv][lr * 16 + 8 + kg * 2 + 1] = pk2(acc1[2], acc1[3]);
        int rkb = __shfl(rk, lane >> 2, 64);
        uint4 val = *(uint4*)&tr[wv][(lane >> 2) * 16 + (lane & 3) * 4];
        *(uint4*)(mg + (size_t)rkb * 32 + (lane & 3) * 8) = val;
    }
}

// ---------------- gather: x' = relu(sum msg[lo..hi) + x@root + bias) ----------
// CSR rows contiguous per node: 4 rows in flight, uint2 (8B) loads per lane,
// 4 fp32 partials/lane -> shfl_xor tree reduce -> redistribute to per-lane o.
struct GatherArgs { const float* root[2]; const float* bias[2]; const int* batch[2]; };
template<int LAST>
__global__ __launch_bounds__(256) void gather_kernel(GatherArgs G,
        const int* __restrict__ ptr, const unsigned short* __restrict__ msg,
        const unsigned short* __restrict__ xin_, unsigned short* __restrict__ xout_,
        float* __restrict__ gbuf) {
    int gw = (blockIdx.x * 256 + threadIdx.x) >> 5;   // node slot (exact grid)
    int l = threadIdx.x & 31;
    int br = gw >= NN, n = gw - br * NN;
    const int* p = ptr + br * (NN + 1);
    int lo = p[n], hi = p[n + 1];
    const unsigned short* m = msg + (size_t)br * NEP * 32;
    int sub = l >> 3;                 // row-in-flight 0..3
    int q   = l & 7;                  // 8B chunk within row
    float ps0 = 0.f, ps1 = 0.f, ps2 = 0.f, ps3 = 0.f;
    for (int j = lo + sub; j < hi; j += 4) {
        uint2 w = *(const uint2*)(m + (size_t)j * 32 + q * 4);
        ps0 += bf2f((unsigned short)(w.x & 0xffffu));
        ps1 += bf2f((unsigned short)(w.x >> 16));
        ps2 += bf2f((unsigned short)(w.y & 0xffffu));
        ps3 += bf2f((unsigned short)(w.y >> 16));
    }
    // reduce over sub (lane bits 3,4 — stays inside the 32-lane team)
    ps0 += __shfl_xor(ps0, 8, 64); ps0 += __shfl_xor(ps0, 16, 64);
    ps1 += __shfl_xor(ps1, 8, 64); ps1 += __shfl_xor(ps1, 16, 64);
    ps2 += __shfl_xor(ps2, 8, 64); ps2 += __shfl_xor(ps2, 16, 64);
    ps3 += __shfl_xor(ps3, 8, 64); ps3 += __shfl_xor(ps3, 16, 64);
    // redistribute: lane o needs ps[o&3] from team-lane (o>>2)
    int srcl = l >> 2;                // within 32-wide groups
    float t0 = __shfl(ps0, srcl, 32);
    float t1 = __shfl(ps1, srcl, 32);
    float t2 = __shfl(ps2, srcl, 32);
    float t3 = __shfl(ps3, srcl, 32);
    int c = l & 3;
    float sum = (c & 2) ? ((c & 1) ? t3 : t2) : ((c & 1) ? t1 : t0);

    float xv = bf2f(xin_[(size_t)br * NPAD * 32 + (size_t)n * 32 + l]);
    const float* R = G.root[br];
    float rsum = 0.f;
    #pragma unroll
    for (int i = 0; i < 32; ++i) rsum += __shfl(xv, i, 32) * R[i * 32 + l];
    float v = fmaxf(sum + rsum + G.bias[br][l], 0.f);
    if (!LAST) {
        xout_[(size_t)br * NPAD * 32 + (size_t)n * 32 + l] = f2bf(v);
    } else {
        int g = G.batch[br][n];
        atomicMax((int*)&gbuf[(size_t)g * 64 + br * 32 + l], __float_as_int(v));
    }
}

// ---------------- final MLP ---------------------------------------------------
__global__ __launch_bounds__(64) void final_mlp_kernel(
        const float* __restrict__ gbuf,
        const float* __restrict__ w0, const float* __restrict__ b0,
        const float* __restrict__ w1v, const float* __restrict__ b1v,
        float* __restrict__ out) {
    int g = blockIdx.x;
    int j = threadIdx.x;
    const float* xr = gbuf + (size_t)g * 64;
    float y = b0[j];
    for (int i = 0; i < 64; ++i) y += xr[i] * w0[i * 64 + j];
    float t = y * w1v[j];
    #pragma unroll
    for (int off = 32; off > 0; off >>= 1) t += __shfl_down(t, off, 64);
    if (j == 0) out[g] = t + b1v[0];
}

static size_t aln(size_t v) { return (v + 255) & ~(size_t)255; }

extern "C" void kernel_launch(void* const* d_in, const int* in_sizes, int n_in,
                              void* d_out, int out_size, void* d_ws, size_t ws_size,
                              hipStream_t stream) {
    (void)in_sizes; (void)n_in; (void)out_size; (void)ws_size;
    char* w = (char*)d_ws;
    unsigned short* Wt  = (unsigned short*)w; w += aln((size_t)S1 * 2);
    unsigned short* xb  = (unsigned short*)w; w += aln((size_t)2 * XL * 2);          // 2 layer slots
    unsigned short* msg = (unsigned short*)w; w += aln((size_t)2 * NEP * 32 * 2);    // 12.8 MB
    int* hist = (int*)w; w += aln((size_t)2 * NN * 4);
    int* ptr  = (int*)w; w += aln((size_t)2 * (NN + 1) * 4);
    int* slot = (int*)w; w += aln((size_t)2 * NE * 4);
    float* gbuf = (float*)w; w += aln((size_t)NG * 64 * 4);

    const int* ep = (const int*)d_in[4];
    const int* ed = (const int*)d_in[5];

    PrepArgs pa;
    for (int L4 = 0; L4 < 4; ++L4) {
        int base = 8 + (L4 >> 1) * 12 + (L4 & 1) * 6;
        pa.w2[L4] = (const float*)d_in[base + 2];
        pa.b2[L4] = (const float*)d_in[base + 3];
    }
    pa.x0[0] = (const float*)d_in[0];
    pa.x0[1] = (const float*)d_in[1];
    prep_kernel<<<(S1 + S2V + S3 + S4 + 255) / 256, 256, 0, stream>>>(pa, Wt, xb, hist, gbuf);

    hist_kernel<<<(2 * NE + 255) / 256, 256, 0, stream>>>(ep, ed, hist, slot);
    scan_kernel<<<2, 1024, 0, stream>>>(hist, ptr);

    EdgeArgs ea; GatherArgs ga;
    for (int br = 0; br < 2; ++br) {
        ea.ea[br]    = (const float*)d_in[2 + br];
        ea.eidx[br]  = (const int*)d_in[4 + br];
        ga.batch[br] = (const int*)d_in[6 + br];
    }
    for (int L = 0; L < 2; ++L) {
        for (int br = 0; br < 2; ++br) {
            int base = 8 + br * 12 + L * 6;
            ea.w1[br]   = (const float*)d_in[base + 0];
            ea.b1[br]   = (const float*)d_in[base + 1];
            ga.root[br] = (const float*)d_in[base + 4];
            ga.bias[br] = (const float*)d_in[base + 5];
        }
        edge_kernel<<<512, 256, 0, stream>>>(ea, L, Wt, xb, ptr, slot, msg);
        if (L == 0)
            gather_kernel<0><<<6250, 256, 0, stream>>>(ga, ptr, msg,
                xb, xb + (size_t)XL, gbuf);
        else
            gather_kernel<1><<<6250, 256, 0, stream>>>(ga, ptr, msg,
                xb + (size_t)XL, nullptr, gbuf);
    }

    final_mlp_kernel<<<NG, 64, 0, stream>>>(gbuf,
        (const float*)d_in[32], (const float*)d_in[33],
        (const float*)d_in[34], (const float*)d_in[35],
        (float*)d_out);
}